// Round 17
// baseline (290.841 us; speedup 1.0000x reference)
//
#include <hip/hip_runtime.h>
#include <hip/hip_fp16.h>

// MPA_16698832847132 — round 17: persistent conv blocks (grid 256, 4 images each)
// with software-pipelined input staging (T14 async-split): next image's 11 float4
// loads issued at conv1 start (no global ops in conv1 -> stay in flight), written
// to inA after the post-conv1 barrier. transF moved to overlay yB (inA free).
// Everything else = r16 (193.2µs).
// Workspace layout unchanged from r16.

typedef __attribute__((ext_vector_type(8))) short bf16x8;
typedef __attribute__((ext_vector_type(8))) _Float16 f16x8;
typedef __attribute__((ext_vector_type(4))) float f32x4;

__device__ __forceinline__ unsigned short f2bf(float f) {
  unsigned u = __builtin_bit_cast(unsigned, f);
  u += 0x7FFFu + ((u >> 16) & 1u);
  return (unsigned short)(u >> 16);
}

// ---------------- weight fragment prep (conv) ---------------------------------
__global__ __launch_bounds__(256) void wprep(
    const float* __restrict__ c1w, const float* __restrict__ c2w,
    unsigned short* __restrict__ w1frag, unsigned short* __restrict__ w2frag)
{
  int t = blockIdx.x * 256 + threadIdx.x;
  if (t < 9216) {
    int j = t & 7, ln = (t >> 3) & 63, ctap = t >> 9;
    int tap = ctap >> 1, ct = ctap & 1;
    int oc = 2 * (ln & 15) + ct, ic = (ln >> 4) * 8 + j;
    w1frag[t] = __half_as_ushort(__float2half(c1w[(oc * 32 + ic) * 9 + tap]));
  }
  if (t < 4608) {
    int j = t & 7, ln = (t >> 3) & 63, tap = t >> 9;
    int oc = (ln & 15) & 7, ic = (ln >> 4) * 8 + j;
    w2frag[t] = __half_as_ushort(__float2half(c2w[(oc * 32 + ic) * 9 + tap]));
  }
}

// -------- f32 -> f16 conversion: x | wqkv | wproj -----------------------------
__global__ __launch_bounds__(256) void cvt_all(
    const float* __restrict__ x, const float* __restrict__ wqkv,
    const float* __restrict__ wproj,
    __half* __restrict__ xh, __half* __restrict__ wqkvh, __half* __restrict__ wprojh)
{
  int t = blockIdx.x * 256 + threadIdx.x;
  const float4* srcp;
  __half* dstp;
  int idx;
  if (t < 1048576)      { srcp = (const float4*)x;     dstp = xh;     idx = t; }
  else if (t < 1245184) { srcp = (const float4*)wqkv;  dstp = wqkvh;  idx = t - 1048576; }
  else                  { srcp = (const float4*)wproj; dstp = wprojh; idx = t - 1245184; }
  float4 v = srcp[idx];
  __half2 h0 = __floats2half2_rn(v.x, v.y);
  __half2 h1 = __floats2half2_rn(v.z, v.w);
  uint2 u; u.x = __builtin_bit_cast(unsigned, h0); u.y = __builtin_bit_cast(unsigned, h1);
  *(uint2*)&dstp[idx * 4] = u;
}

// ------- C[M][N] = A[M][K] * B[N][K]^T (+bias); A,B f16 -----------------------
template<bool OUT_BF16>
__global__ __launch_bounds__(256) void gemm_f16_bt(
    const __half* __restrict__ Ah, const __half* __restrict__ Bh,
    void* __restrict__ Cv, const float* __restrict__ bias,
    int M, int N, int K)
{
  __shared__ __align__(16) _Float16 As[128 * 40];
  __shared__ __align__(16) _Float16 Bs[128 * 40];
  const int tid = threadIdx.x;
  const int wv = tid >> 6, ln = tid & 63, lr = ln & 15, lq = ln >> 4;
  const int wm = wv >> 1, wn = wv & 1;
  const int m0 = blockIdx.y * 128, n0 = blockIdx.x * 128;

  f32x4 acc[4][4];
#pragma unroll
  for (int i = 0; i < 4; i++)
#pragma unroll
    for (int j = 0; j < 4; j++) acc[i][j] = (f32x4){0.f, 0.f, 0.f, 0.f};

  const int sr = tid >> 1, sk = (tid & 1) * 16;

  for (int k0 = 0; k0 < K; k0 += 32) {
    uint4 ha0 = *(const uint4*)(Ah + (size_t)(m0 + sr) * K + k0 + sk);
    uint4 ha1 = *(const uint4*)(Ah + (size_t)(m0 + sr) * K + k0 + sk + 8);
    uint4 hb0 = *(const uint4*)(Bh + (size_t)(n0 + sr) * K + k0 + sk);
    uint4 hb1 = *(const uint4*)(Bh + (size_t)(n0 + sr) * K + k0 + sk + 8);
    __syncthreads();
    *(uint4*)&As[sr * 40 + sk] = ha0;
    *(uint4*)&As[sr * 40 + sk + 8] = ha1;
    *(uint4*)&Bs[sr * 40 + sk] = hb0;
    *(uint4*)&Bs[sr * 40 + sk + 8] = hb1;
    __syncthreads();
    f16x8 af[4], bf[4];
#pragma unroll
    for (int mf = 0; mf < 4; mf++)
      af[mf] = *(const f16x8*)&As[(wm * 64 + mf * 16 + lr) * 40 + lq * 8];
#pragma unroll
    for (int nf = 0; nf < 4; nf++)
      bf[nf] = *(const f16x8*)&Bs[(wn * 64 + nf * 16 + lr) * 40 + lq * 8];
#pragma unroll
    for (int mf = 0; mf < 4; mf++)
#pragma unroll
      for (int nf = 0; nf < 4; nf++)
        acc[mf][nf] = __builtin_amdgcn_mfma_f32_16x16x32_f16(af[mf], bf[nf], acc[mf][nf], 0, 0, 0);
  }

#pragma unroll
  for (int mf = 0; mf < 4; mf++)
#pragma unroll
    for (int reg = 0; reg < 4; reg++) {
      const int row = m0 + wm * 64 + mf * 16 + lq * 4 + reg;
#pragma unroll
      for (int nf = 0; nf < 4; nf++) {
        const int col = n0 + wn * 64 + nf * 16 + lr;
        float v = acc[mf][nf][reg];
        if (bias) v += bias[col];
        if (OUT_BF16) ((unsigned short*)Cv)[(size_t)row * N + col] = f2bf(v);
        else          ((float*)Cv)[(size_t)row * N + col] = v;
      }
    }
}

// ---- persistent fused conv: grid 256, 4 images/block, pipelined staging -------
// LDS: inA[4][1296][8] @0 (82,944) | yB[4][1156][8] @82,944 (73,984)
//      statA f32[64] @156,928 | aL/cL @157,184 -> 157,440 B
// transF f32[8][1032] overlays *yB* (33KB; written only after conv2's yB reads),
// so inA is free from the post-conv1 barrier onward -> next image staged there.
__global__ __launch_bounds__(1024, 1) void conv_fused5(
    const float* __restrict__ rpe,
    const unsigned short* __restrict__ w1frag, const unsigned short* __restrict__ w2frag,
    const float* __restrict__ g1, const float* __restrict__ b1,
    const float* __restrict__ g2, const float* __restrict__ b2,
    __half* __restrict__ wout)
{
  extern __shared__ __align__(16) char smem[];
  unsigned short* inA = (unsigned short*)smem;              // 4 x 10368 halves
  unsigned short* yB  = (unsigned short*)(smem + 82944);    // 4 x 9248 halves
  float* statA = (float*)(smem + 156928);                   // 64
  float* aL    = (float*)(smem + 157184);                   // 32
  float* cL    = aL + 32;                                   // 32
  float* transF = (float*)(smem + 82944);                   // overlay on yB

  const int tid = threadIdx.x;
  const int wv = tid >> 6, ln = tid & 63;
  const int lr = ln & 15, lq = ln >> 4;

  if (tid < 64) statA[tid] = 0.f;

  // prologue: stage image p0 = blockIdx.x
  {
    const int p = blockIdx.x;
    const float* src = rpe + (size_t)(((p >> 5) + 2) * 36 + (p & 31) + 2) * 41472;
    for (int e = tid; e < 10368; e += 1024) {
      float4 v = *(const float4*)(src + e * 4);
      __half2 h0 = __floats2half2_rn(v.x, v.y);
      __half2 h1 = __floats2half2_rn(v.z, v.w);
      uint2 u; u.x = __builtin_bit_cast(unsigned, h0); u.y = __builtin_bit_cast(unsigned, h1);
      *(uint2*)&inA[((e & 7) >> 1) * 10368 + (e >> 3) * 8 + (e & 1) * 4] = u;
    }
  }
  __syncthreads();

  constexpr int OFF1[9] = {0, 8, 16, 288, 296, 304, 576, 584, 592};
  constexpr int OFF2[9] = {0, 8, 16, 272, 280, 288, 544, 552, 560};
  const unsigned short* inAg = inA + lq * 10368;
  const unsigned short* yBg  = yB + lq * 9248;

  for (int it = 0; it < 4; ++it) {
    const int p = blockIdx.x + (it << 8);

    // ---- issue next image's loads NOW (no global ops inside conv1 -> in flight)
    float4 stg[11];
    if (it < 3) {
      const int pn = p + 256;
      const float* srcn = rpe + (size_t)(((pn >> 5) + 2) * 36 + (pn & 31) + 2) * 41472;
#pragma unroll
      for (int k = 0; k < 10; k++) stg[k] = *(const float4*)(srcn + (tid + k * 1024) * 4);
      if (tid < 128) stg[10] = *(const float4*)(srcn + (tid + 10240) * 4);
    }

    // ---- w1 fragments (compiler remats from L1 as needed)
    f16x8 w1f[2][9];
#pragma unroll
    for (int ct = 0; ct < 2; ct++)
#pragma unroll
      for (int tap = 0; tap < 9; tap++)
        w1f[ct][tap] = *(const f16x8*)&w1frag[((tap * 2 + ct) * 64 + ln) * 8];

    // ---- conv1: 2-tile pairs + tail
    float s0 = 0.f, q0 = 0.f, s1 = 0.f, q1 = 0.f;
    for (int t0 = wv; t0 < 64; t0 += 32) {
      const int tA = t0, tB = t0 + 16;
      const int mA = tA * 16 + lr, mB = tB * 16 + lr;
      const unsigned short* abA = inAg + ((mA / 34) * 36 + (mA % 34)) * 8;
      const unsigned short* abB = inAg + ((mB / 34) * 36 + (mB % 34)) * 8;
      f32x4 cA0 = {0.f,0.f,0.f,0.f}, cA1 = {0.f,0.f,0.f,0.f};
      f32x4 cB0 = {0.f,0.f,0.f,0.f}, cB1 = {0.f,0.f,0.f,0.f};
#pragma unroll
      for (int tap = 0; tap < 9; tap++) {
        f16x8 avA = *(const f16x8*)(abA + OFF1[tap]);
        f16x8 avB = *(const f16x8*)(abB + OFF1[tap]);
        cA0 = __builtin_amdgcn_mfma_f32_16x16x32_f16(avA, w1f[0][tap], cA0, 0, 0, 0);
        cA1 = __builtin_amdgcn_mfma_f32_16x16x32_f16(avA, w1f[1][tap], cA1, 0, 0, 0);
        cB0 = __builtin_amdgcn_mfma_f32_16x16x32_f16(avB, w1f[0][tap], cB0, 0, 0, 0);
        cB1 = __builtin_amdgcn_mfma_f32_16x16x32_f16(avB, w1f[1][tap], cB1, 0, 0, 0);
      }
#pragma unroll
      for (int r = 0; r < 4; r++) {
        int moA = tA * 16 + lq * 4 + r;
        float v0 = cA0[r], v1 = cA1[r];
        unsigned u = (unsigned)__half_as_ushort(__float2half(v0))
                   | ((unsigned)__half_as_ushort(__float2half(v1)) << 16);
        *(unsigned*)&yB[(lr >> 2) * 9248 + moA * 8 + ((lr * 2) & 7)] = u;
        s0 += v0; q0 += v0 * v0; s1 += v1; q1 += v1 * v1;
        int moB = tB * 16 + lq * 4 + r;
        float w0 = cB0[r], w1 = cB1[r];
        unsigned u2 = (unsigned)__half_as_ushort(__float2half(w0))
                    | ((unsigned)__half_as_ushort(__float2half(w1)) << 16);
        *(unsigned*)&yB[(lr >> 2) * 9248 + moB * 8 + ((lr * 2) & 7)] = u2;
        s0 += w0; q0 += w0 * w0; s1 += w1; q1 += w1 * w1;
      }
    }
    if (wv < 9) {
      int t = wv + 64;
      int m = t * 16 + lr;
      int ms = m < 1155 ? m : 1155;
      const unsigned short* ab = inAg + ((ms / 34) * 36 + (ms % 34)) * 8;
      f32x4 c0 = {0.f,0.f,0.f,0.f}, c1v = {0.f,0.f,0.f,0.f};
#pragma unroll
      for (int tap = 0; tap < 9; tap++) {
        f16x8 av = *(const f16x8*)(ab + OFF1[tap]);
        c0  = __builtin_amdgcn_mfma_f32_16x16x32_f16(av, w1f[0][tap], c0, 0, 0, 0);
        c1v = __builtin_amdgcn_mfma_f32_16x16x32_f16(av, w1f[1][tap], c1v, 0, 0, 0);
      }
#pragma unroll
      for (int r = 0; r < 4; r++) {
        int mo = t * 16 + lq * 4 + r;
        if (mo < 1156) {
          float v0 = c0[r], v1 = c1v[r];
          unsigned u = (unsigned)__half_as_ushort(__float2half(v0))
                     | ((unsigned)__half_as_ushort(__float2half(v1)) << 16);
          *(unsigned*)&yB[(lr >> 2) * 9248 + mo * 8 + ((lr * 2) & 7)] = u;
          s0 += v0; q0 += v0 * v0; s1 += v1; q1 += v1 * v1;
        }
      }
    }
#pragma unroll
    for (int off = 16; off < 64; off <<= 1) {
      s0 += __shfl_xor(s0, off); q0 += __shfl_xor(q0, off);
      s1 += __shfl_xor(s1, off); q1 += __shfl_xor(q1, off);
    }
    if (ln < 16) {
      atomicAdd(&statA[ln], s0);      atomicAdd(&statA[16 + ln], q0);
      atomicAdd(&statA[32 + ln], s1); atomicAdd(&statA[48 + ln], q1);
    }
    __syncthreads();   // barrier A: all inA reads done (also drains stg loads)

    // ---- write staged registers -> inA (next image)
    if (it < 3) {
#pragma unroll
      for (int k = 0; k < 10; k++) {
        int e = tid + k * 1024;
        __half2 h0 = __floats2half2_rn(stg[k].x, stg[k].y);
        __half2 h1 = __floats2half2_rn(stg[k].z, stg[k].w);
        uint2 u; u.x = __builtin_bit_cast(unsigned, h0); u.y = __builtin_bit_cast(unsigned, h1);
        *(uint2*)&inA[((e & 7) >> 1) * 10368 + (e >> 3) * 8 + (e & 1) * 4] = u;
      }
      if (tid < 128) {
        int e = tid + 10240;
        __half2 h0 = __floats2half2_rn(stg[10].x, stg[10].y);
        __half2 h1 = __floats2half2_rn(stg[10].z, stg[10].w);
        uint2 u; u.x = __builtin_bit_cast(unsigned, h0); u.y = __builtin_bit_cast(unsigned, h1);
        *(uint2*)&inA[((e & 7) >> 1) * 10368 + (e >> 3) * 8 + (e & 1) * 4] = u;
      }
    }
    // ---- IN1 finalize
    if (tid < 32) {
      int cti = tid >> 4, lri = tid & 15;   // ch = 2*lri + cti
      float s = statA[cti * 32 + lri];
      float q = statA[cti * 32 + 16 + lri];
      int ch = 2 * lri + cti;
      float mu = s * (1.f / 1156.f);
      float var = q * (1.f / 1156.f) - mu * mu;
      float a_ = rsqrtf(var + 1e-5f) * g1[ch];
      aL[ch] = a_; cL[ch] = b1[ch] - mu * a_;
    }
    if (tid < 16) statA[tid] = 0.f;  // IN2 slots (same-thread order safe)
    __syncthreads();   // barrier B

    // ---- normalize + relu RMW on yB
    {
      int g = tid >> 8, ocb = g * 8;
      unsigned short* yg = yB + g * 9248;
      for (int pix = (tid & 255); pix < 1156; pix += 256) {
        f16x8 raw = *(const f16x8*)&yg[pix * 8];
        f16x8 outv;
#pragma unroll
        for (int e = 0; e < 8; e++) {
          float v = (float)raw[e];
          outv[e] = (_Float16)fmaxf(v * aL[ocb + e] + cL[ocb + e], 0.f);
        }
        *(f16x8*)&yg[pix * 8] = outv;
      }
    }
    __syncthreads();   // barrier C

    // ---- conv2 (zsave in regs; transF written only after barrier D)
    f16x8 w2f[9];
#pragma unroll
    for (int tap = 0; tap < 9; tap++)
      w2f[tap] = *(const f16x8*)&w2frag[(tap * 64 + ln) * 8];

    f32x4 zsave[4];
    float s2 = 0.f, q2 = 0.f;
#pragma unroll
    for (int t0 = 0; t0 < 2; t0++) {
      const int tA = wv + t0 * 32, tB = tA + 16;
      const int mA = tA * 16 + lr, mB = tB * 16 + lr;
      const unsigned short* abA = yBg + ((mA >> 5) * 34 + (mA & 31)) * 8;
      const unsigned short* abB = yBg + ((mB >> 5) * 34 + (mB & 31)) * 8;
      f32x4 ccA = {0.f,0.f,0.f,0.f}, ccB = {0.f,0.f,0.f,0.f};
#pragma unroll
      for (int tap = 0; tap < 9; tap++) {
        f16x8 avA = *(const f16x8*)(abA + OFF2[tap]);
        f16x8 avB = *(const f16x8*)(abB + OFF2[tap]);
        ccA = __builtin_amdgcn_mfma_f32_16x16x32_f16(avA, w2f[tap], ccA, 0, 0, 0);
        ccB = __builtin_amdgcn_mfma_f32_16x16x32_f16(avB, w2f[tap], ccB, 0, 0, 0);
      }
      zsave[t0 * 2] = ccA; zsave[t0 * 2 + 1] = ccB;
#pragma unroll
      for (int r = 0; r < 4; r++) {
        s2 += ccA[r] + ccB[r]; q2 += ccA[r] * ccA[r] + ccB[r] * ccB[r];
      }
    }
#pragma unroll
    for (int off = 16; off < 64; off <<= 1) {
      s2 += __shfl_xor(s2, off); q2 += __shfl_xor(q2, off);
    }
    if (ln < 8) { atomicAdd(&statA[ln], s2); atomicAdd(&statA[8 + ln], q2); }
    __syncthreads();   // barrier D: yB reads complete -> transF overlay safe

    if (lr < 8) {
#pragma unroll
      for (int t0 = 0; t0 < 2; t0++) {
        const int tA = wv + t0 * 32, tB = tA + 16;
#pragma unroll
        for (int r = 0; r < 4; r++) {
          transF[lr * 1032 + tA * 16 + lq * 4 + r] = zsave[t0 * 2][r];
          transF[lr * 1032 + tB * 16 + lq * 4 + r] = zsave[t0 * 2 + 1][r];
        }
      }
    }
    if (tid < 8) {
      float s = statA[tid], q = statA[8 + tid];
      float mu = s * (1.f / 1024.f);
      float var = q * (1.f / 1024.f) - mu * mu;
      float a_ = rsqrtf(var + 1e-5f) * g2[tid];
      aL[tid] = a_; cL[tid] = b2[tid] - mu * a_;
    }
    __syncthreads();   // barrier E

    // ---- sigmoid + f16 store; re-zero statA for next image
    {
      int oc = tid >> 7, p8 = (tid & 127) << 3;
      float a_ = aL[oc], c_ = cL[oc];
      f16x8 o;
#pragma unroll
      for (int e = 0; e < 8; e++) {
        float v = transF[oc * 1032 + p8 + e];
        o[e] = (_Float16)(1.f / (1.f + __expf(-(v * a_ + c_))));
      }
      *(f16x8*)&wout[((size_t)oc << 20) + ((size_t)p << 10) + p8] = o;
    }
    if (tid < 64) statA[tid] = 0.f;
    __syncthreads();   // barrier F: statA zero + transF reads done before next iter
  }
}

// ---------------- fused attention (r16 verbatim) -------------------------------
__global__ __launch_bounds__(256) void attn_kernel(
    const unsigned short* __restrict__ qkv,  // bf16 bits [8192][1536]
    const __half* __restrict__ wppe,         // f16 [8][1024][1024]
    __half* __restrict__ oh)                 // f16 [8192][512] = (b,n,h,d)
{
  __shared__ __align__(16) unsigned short k_lds[64 * 72];
  __shared__ __align__(16) unsigned short v_lds[64 * 72]; // transposed [d][m ^ swz]
  __shared__ __align__(16) unsigned short p_lds[4 * 16 * 72];
  const int tid = threadIdx.x;
  const int wv = tid >> 6, ln = tid & 63;
  const int lr = ln & 15, lq = ln >> 4;
  const int b = blockIdx.y >> 3, h = blockIdx.y & 7;
  const int n0 = blockIdx.x << 6;

  const size_t qoff = (size_t)((b << 10) + n0 + (wv << 4) + lr) * 1536 + (h << 6);
  bf16x8 qf0 = *(const bf16x8*)(qkv + qoff + lq * 8);
  bf16x8 qf1 = *(const bf16x8*)(qkv + qoff + 32 + lq * 8);

  f32x4 acc[4];
#pragma unroll
  for (int dt = 0; dt < 4; dt++) acc[dt] = (f32x4){0.f, 0.f, 0.f, 0.f};
  float den[4] = {0.f, 0.f, 0.f, 0.f};
  const __half* wp = wppe + ((size_t)h << 20);

  for (int m0 = 0; m0 < 1024; m0 += 64) {
    __syncthreads();
    float wpre[4][4];
#pragma unroll
    for (int mt = 0; mt < 4; mt++)
#pragma unroll
      for (int reg = 0; reg < 4; reg++)
        wpre[mt][reg] = __half2float(
            wp[(size_t)(n0 + (wv << 4) + lq * 4 + reg) * 1024 + (m0 + mt * 16 + lr)]);
    for (int t = tid; t < 512; t += 256) {
      int m = t >> 3, dq = t & 7;
      const unsigned short* kr = qkv + (size_t)((b << 10) + m0 + m) * 1536 + 512 + (h << 6) + dq * 8;
      *(uint4*)&k_lds[m * 72 + dq * 8] = *(const uint4*)kr;
      uint4 vvv = *(const uint4*)(kr + 512);
      unsigned short tmp[8];
      *(uint4*)tmp = vvv;
#pragma unroll
      for (int i = 0; i < 8; i++) {
        int d = dq * 8 + i;
        v_lds[d * 72 + (m ^ (((d >> 3) & 7) << 3))] = tmp[i];
      }
    }
    __syncthreads();

    f32x4 s[4];
#pragma unroll
    for (int mt = 0; mt < 4; mt++) {
      const unsigned short* kb = &k_lds[(mt * 16 + lr) * 72 + lq * 8];
      f32x4 cz = (f32x4){0.f, 0.f, 0.f, 0.f};
      cz = __builtin_amdgcn_mfma_f32_16x16x32_bf16(qf0, *(const bf16x8*)kb, cz, 0, 0, 0);
      cz = __builtin_amdgcn_mfma_f32_16x16x32_bf16(qf1, *(const bf16x8*)(kb + 32), cz, 0, 0, 0);
      s[mt] = cz;
    }
#pragma unroll
    for (int mt = 0; mt < 4; mt++)
#pragma unroll
      for (int reg = 0; reg < 4; reg++) {
        int rrow = lq * 4 + reg;
        float pv = wpre[mt][reg] * __expf(s[mt][reg] * 0.125f);
        den[reg] += pv;
        p_lds[((wv << 4) + rrow) * 72 + mt * 16 + lr] = f2bf(pv);
      }
    const unsigned short* pb = &p_lds[((wv << 4) + lr) * 72];
    bf16x8 pa0 = *(const bf16x8*)(pb + lq * 8);
    bf16x8 pa1 = *(const bf16x8*)(pb + 32 + lq * 8);
#pragma unroll
    for (int dt = 0; dt < 4; dt++) {
      int d = dt * 16 + lr;
      int sw = ((d >> 3) & 7) << 3;
      const unsigned short* vb = &v_lds[d * 72];
      acc[dt] = __builtin_amdgcn_mfma_f32_16x16x32_bf16(pa0, *(const bf16x8*)(vb + ((lq * 8) ^ sw)), acc[dt], 0, 0, 0);
      acc[dt] = __builtin_amdgcn_mfma_f32_16x16x32_bf16(pa1, *(const bf16x8*)(vb + ((32 + lq * 8) ^ sw)), acc[dt], 0, 0, 0);
    }
  }
#pragma unroll
  for (int off = 1; off < 16; off <<= 1)
#pragma unroll
    for (int reg = 0; reg < 4; reg++) den[reg] += __shfl_xor(den[reg], off);
#pragma unroll
  for (int dt = 0; dt < 4; dt++)
#pragma unroll
    for (int reg = 0; reg < 4; reg++) {
      size_t row = (size_t)((b << 10) + n0 + (wv << 4) + lq * 4 + reg);
      oh[row * 512 + (h << 6) + dt * 16 + lr] = __float2half(acc[dt][reg] / den[reg]);
    }
}

// ---------------------------------------------------------------------------
extern "C" void kernel_launch(void* const* d_in, const int* in_sizes, int n_in,
                              void* d_out, int out_size, void* d_ws, size_t ws_size,
                              hipStream_t stream) {
  (void)in_sizes; (void)n_in; (void)out_size; (void)ws_size;
  const float* x     = (const float*)d_in[0];
  const float* rpe   = (const float*)d_in[1];
  const float* wqkv  = (const float*)d_in[2];
  const float* wproj = (const float*)d_in[3];
  const float* bproj = (const float*)d_in[4];
  const float* c1w   = (const float*)d_in[5];
  // d_in[6] = c1b: cancels exactly in the following instance-norm
  const float* g1w   = (const float*)d_in[7];
  const float* g1b   = (const float*)d_in[8];
  const float* c2w   = (const float*)d_in[9];
  // d_in[10] = c2b: cancels likewise
  const float* g2w   = (const float*)d_in[11];
  const float* g2b   = (const float*)d_in[12];
  float* out = (float*)d_out;

  char* ws = (char*)d_ws;
  unsigned short* qkv_bf = (unsigned short*)ws;              // 25,165,824 B
  __half* wppe_h = (__half*)(ws + 25165824);                 // 16,777,216 B
  __half* oh_h   = (__half*)(ws + 41943040);                 // 8,388,608 B
  unsigned short* w1frag = (unsigned short*)(ws + 50331648); // 18,432 B
  unsigned short* w2frag = (unsigned short*)(ws + 50350080); // 9,216 B
  __half* wqkvh  = (__half*)(ws + 50359296);                 // 1,572,864 B
  __half* wprojh = (__half*)(ws + 51932160);                 // 524,288 B
  __half* xh     = (__half*)(ws + 52456448);                 // 8,388,608 B

  // 0) bake conv fragments + convert x/wqkv/wproj to f16
  wprep<<<36, 256, 0, stream>>>(c1w, c2w, w1frag, w2frag);
  cvt_all<<<5120, 256, 0, stream>>>(x, wqkv, wproj, xh, wqkvh, wprojh);

  // 1) qkv = x @ wqkv^T -> bf16 (A f16, B f16)
  gemm_f16_bt<true><<<dim3(12, 64), 256, 0, stream>>>(
      xh, wqkvh, qkv_bf, nullptr, 8192, 1536, 512);

  // 2) persistent fused conv (grid 256, 4 images/block, pipelined staging)
  const int ldsC = 157440;
  hipFuncSetAttribute(reinterpret_cast<const void*>(&conv_fused5),
                      hipFuncAttributeMaxDynamicSharedMemorySize, ldsC);
  conv_fused5<<<256, 1024, ldsC, stream>>>(rpe, w1frag, w2frag, g1w, g1b, g2w, g2b, wppe_h);

  // 3) fused attention -> oh f16
  attn_kernel<<<dim3(16, 64), 256, 0, stream>>>(qkv_bf, wppe_h, oh_h);

  // 4) out = oh @ wproj^T + bproj (A f16, B f16)
  gemm_f16_bt<false><<<dim3(4, 64), 256, 0, stream>>>(
      oh_h, wprojh, out, bproj, 8192, 512, 512);
}

// Round 18
// 189.760 us; speedup vs baseline: 1.5327x; 1.5327x over previous
//
#include <hip/hip_runtime.h>
#include <hip/hip_fp16.h>

// MPA_16698832847132 — round 18: r16 (193.2µs best) + conv __launch_bounds__(1024,4).
// Diagnosis: dynamic LDS hides the 157KB from regalloc -> compiler budgets VGPR
// for 8 waves/EU (64 cap) and remats weight fragments from L1 every tile.
// (1024,4) raises the cap to 128 (LDS pins us at 4 waves/EU regardless), letting
// w1f/w2f stay resident. wprep merged into cvt_all (one fewer dispatch).
// Workspace: qkv bf16 @0 | w f16 @25,165,824 | oh f16 @41,943,040 |
//   w1frag @50,331,648 | w2frag @50,350,080 | wqkvh @50,359,296 |
//   wprojh @51,932,160 | xh @52,456,448

typedef __attribute__((ext_vector_type(8))) short bf16x8;
typedef __attribute__((ext_vector_type(8))) _Float16 f16x8;
typedef __attribute__((ext_vector_type(4))) float f32x4;

__device__ __forceinline__ unsigned short f2bf(float f) {
  unsigned u = __builtin_bit_cast(unsigned, f);
  u += 0x7FFFu + ((u >> 16) & 1u);
  return (unsigned short)(u >> 16);
}

// ---- prep: conv fragment bake + f32->f16 conversion of x/wqkv/wproj ----------
__global__ __launch_bounds__(256) void prep_all(
    const float* __restrict__ c1w, const float* __restrict__ c2w,
    const float* __restrict__ x, const float* __restrict__ wqkv,
    const float* __restrict__ wproj,
    unsigned short* __restrict__ w1frag, unsigned short* __restrict__ w2frag,
    __half* __restrict__ xh, __half* __restrict__ wqkvh, __half* __restrict__ wprojh)
{
  int t = blockIdx.x * 256 + threadIdx.x;   // grid 5184 -> 1,327,104 threads
  if (t < 1048576) {
    float4 v = ((const float4*)x)[t];
    __half2 h0 = __floats2half2_rn(v.x, v.y);
    __half2 h1 = __floats2half2_rn(v.z, v.w);
    uint2 u; u.x = __builtin_bit_cast(unsigned, h0); u.y = __builtin_bit_cast(unsigned, h1);
    *(uint2*)&xh[t * 4] = u;
  } else if (t < 1245184) {
    int i = t - 1048576;
    float4 v = ((const float4*)wqkv)[i];
    __half2 h0 = __floats2half2_rn(v.x, v.y);
    __half2 h1 = __floats2half2_rn(v.z, v.w);
    uint2 u; u.x = __builtin_bit_cast(unsigned, h0); u.y = __builtin_bit_cast(unsigned, h1);
    *(uint2*)&wqkvh[i * 4] = u;
  } else if (t < 1310720) {
    int i = t - 1245184;
    float4 v = ((const float4*)wproj)[i];
    __half2 h0 = __floats2half2_rn(v.x, v.y);
    __half2 h1 = __floats2half2_rn(v.z, v.w);
    uint2 u; u.x = __builtin_bit_cast(unsigned, h0); u.y = __builtin_bit_cast(unsigned, h1);
    *(uint2*)&wprojh[i * 4] = u;
  } else {
    int i = t - 1310720;                     // 0..16383
    if (i < 9216) {
      int j = i & 7, ln = (i >> 3) & 63, ctap = i >> 9;
      int tap = ctap >> 1, ct = ctap & 1;
      int oc = 2 * (ln & 15) + ct, ic = (ln >> 4) * 8 + j;
      w1frag[i] = __half_as_ushort(__float2half(c1w[(oc * 32 + ic) * 9 + tap]));
    }
    if (i < 4608) {
      int j = i & 7, ln = (i >> 3) & 63, tap = i >> 9;
      int oc = (ln & 15) & 7, ic = (ln >> 4) * 8 + j;
      w2frag[i] = __half_as_ushort(__float2half(c2w[(oc * 32 + ic) * 9 + tap]));
    }
  }
}

// ------- C[M][N] = A[M][K] * B[N][K]^T (+bias); A,B f16 -----------------------
template<bool OUT_BF16>
__global__ __launch_bounds__(256) void gemm_f16_bt(
    const __half* __restrict__ Ah, const __half* __restrict__ Bh,
    void* __restrict__ Cv, const float* __restrict__ bias,
    int M, int N, int K)
{
  __shared__ __align__(16) _Float16 As[128 * 40];
  __shared__ __align__(16) _Float16 Bs[128 * 40];
  const int tid = threadIdx.x;
  const int wv = tid >> 6, ln = tid & 63, lr = ln & 15, lq = ln >> 4;
  const int wm = wv >> 1, wn = wv & 1;
  const int m0 = blockIdx.y * 128, n0 = blockIdx.x * 128;

  f32x4 acc[4][4];
#pragma unroll
  for (int i = 0; i < 4; i++)
#pragma unroll
    for (int j = 0; j < 4; j++) acc[i][j] = (f32x4){0.f, 0.f, 0.f, 0.f};

  const int sr = tid >> 1, sk = (tid & 1) * 16;

  for (int k0 = 0; k0 < K; k0 += 32) {
    uint4 ha0 = *(const uint4*)(Ah + (size_t)(m0 + sr) * K + k0 + sk);
    uint4 ha1 = *(const uint4*)(Ah + (size_t)(m0 + sr) * K + k0 + sk + 8);
    uint4 hb0 = *(const uint4*)(Bh + (size_t)(n0 + sr) * K + k0 + sk);
    uint4 hb1 = *(const uint4*)(Bh + (size_t)(n0 + sr) * K + k0 + sk + 8);
    __syncthreads();
    *(uint4*)&As[sr * 40 + sk] = ha0;
    *(uint4*)&As[sr * 40 + sk + 8] = ha1;
    *(uint4*)&Bs[sr * 40 + sk] = hb0;
    *(uint4*)&Bs[sr * 40 + sk + 8] = hb1;
    __syncthreads();
    f16x8 af[4], bf[4];
#pragma unroll
    for (int mf = 0; mf < 4; mf++)
      af[mf] = *(const f16x8*)&As[(wm * 64 + mf * 16 + lr) * 40 + lq * 8];
#pragma unroll
    for (int nf = 0; nf < 4; nf++)
      bf[nf] = *(const f16x8*)&Bs[(wn * 64 + nf * 16 + lr) * 40 + lq * 8];
#pragma unroll
    for (int mf = 0; mf < 4; mf++)
#pragma unroll
      for (int nf = 0; nf < 4; nf++)
        acc[mf][nf] = __builtin_amdgcn_mfma_f32_16x16x32_f16(af[mf], bf[nf], acc[mf][nf], 0, 0, 0);
  }

#pragma unroll
  for (int mf = 0; mf < 4; mf++)
#pragma unroll
    for (int reg = 0; reg < 4; reg++) {
      const int row = m0 + wm * 64 + mf * 16 + lq * 4 + reg;
#pragma unroll
      for (int nf = 0; nf < 4; nf++) {
        const int col = n0 + wn * 64 + nf * 16 + lr;
        float v = acc[mf][nf][reg];
        if (bias) v += bias[col];
        if (OUT_BF16) ((unsigned short*)Cv)[(size_t)row * N + col] = f2bf(v);
        else          ((float*)Cv)[(size_t)row * N + col] = v;
      }
    }
}

// ---------------- fused conv1+IN1+relu+conv2+IN2+sigmoid ----------------------
// r14/r16 structure; __launch_bounds__(1024,4) -> 128-VGPR budget so weight
// fragments stay register-resident (dynamic LDS hid the 1-block/CU reality).
__global__ __launch_bounds__(1024, 4) void conv_fused3(
    const float* __restrict__ rpe,
    const unsigned short* __restrict__ w1frag, const unsigned short* __restrict__ w2frag,
    const float* __restrict__ g1, const float* __restrict__ b1,
    const float* __restrict__ g2, const float* __restrict__ b2,
    __half* __restrict__ wout)
{
  extern __shared__ __align__(16) char smem[];
  unsigned short* inA = (unsigned short*)smem;              // 4 x 10368 halves
  unsigned short* yB  = (unsigned short*)(smem + 82944);    // 4 x 9248 halves
  float* statA = (float*)(smem + 156928);                   // 64
  float* aL    = (float*)(smem + 157184);                   // 32
  float* cL    = aL + 32;                                   // 32
  float* transF = (float*)smem;                             // overlay [8][1032]

  const int tid = threadIdx.x;
  const int wv = tid >> 6, ln = tid & 63;
  const int lr = ln & 15, lq = ln >> 4;
  const int p = blockIdx.x;

  if (tid < 64) statA[tid] = 0.f;

  const float* src = rpe + (size_t)(((p >> 5) + 2) * 36 + (p & 31) + 2) * 41472;
  for (int t = tid; t < 10368; t += 1024) {
    int pix = t >> 3, dq = (t & 7) << 2;
    float4 v = *(const float4*)(src + pix * 32 + dq);
    __half2 h0 = __floats2half2_rn(v.x, v.y);
    __half2 h1 = __floats2half2_rn(v.z, v.w);
    uint2 u; u.x = __builtin_bit_cast(unsigned, h0); u.y = __builtin_bit_cast(unsigned, h1);
    *(uint2*)&inA[(dq >> 3) * 10368 + pix * 8 + (dq & 7)] = u;
  }

  f16x8 w1f[2][9];
#pragma unroll
  for (int ct = 0; ct < 2; ct++)
#pragma unroll
    for (int tap = 0; tap < 9; tap++)
      w1f[ct][tap] = *(const f16x8*)&w1frag[((tap * 2 + ct) * 64 + ln) * 8];
  __syncthreads();

  constexpr int OFF1[9] = {0, 8, 16, 288, 296, 304, 576, 584, 592};
  const unsigned short* inAg = inA + lq * 10368;
  float s0 = 0.f, q0 = 0.f, s1 = 0.f, q1 = 0.f;
  for (int t0 = wv; t0 < 64; t0 += 32) {
    const int tA = t0, tB = t0 + 16;
    const int mA = tA * 16 + lr, mB = tB * 16 + lr;
    const unsigned short* abA = inAg + ((mA / 34) * 36 + (mA % 34)) * 8;
    const unsigned short* abB = inAg + ((mB / 34) * 36 + (mB % 34)) * 8;
    f32x4 cA0 = {0.f,0.f,0.f,0.f}, cA1 = {0.f,0.f,0.f,0.f};
    f32x4 cB0 = {0.f,0.f,0.f,0.f}, cB1 = {0.f,0.f,0.f,0.f};
#pragma unroll
    for (int tap = 0; tap < 9; tap++) {
      f16x8 avA = *(const f16x8*)(abA + OFF1[tap]);
      f16x8 avB = *(const f16x8*)(abB + OFF1[tap]);
      cA0 = __builtin_amdgcn_mfma_f32_16x16x32_f16(avA, w1f[0][tap], cA0, 0, 0, 0);
      cA1 = __builtin_amdgcn_mfma_f32_16x16x32_f16(avA, w1f[1][tap], cA1, 0, 0, 0);
      cB0 = __builtin_amdgcn_mfma_f32_16x16x32_f16(avB, w1f[0][tap], cB0, 0, 0, 0);
      cB1 = __builtin_amdgcn_mfma_f32_16x16x32_f16(avB, w1f[1][tap], cB1, 0, 0, 0);
    }
#pragma unroll
    for (int r = 0; r < 4; r++) {
      int moA = tA * 16 + lq * 4 + r;
      float v0 = cA0[r], v1 = cA1[r];
      unsigned u = (unsigned)__half_as_ushort(__float2half(v0))
                 | ((unsigned)__half_as_ushort(__float2half(v1)) << 16);
      *(unsigned*)&yB[(lr >> 2) * 9248 + moA * 8 + ((lr * 2) & 7)] = u;
      s0 += v0; q0 += v0 * v0; s1 += v1; q1 += v1 * v1;
      int moB = tB * 16 + lq * 4 + r;
      float w0 = cB0[r], w1 = cB1[r];
      unsigned u2 = (unsigned)__half_as_ushort(__float2half(w0))
                  | ((unsigned)__half_as_ushort(__float2half(w1)) << 16);
      *(unsigned*)&yB[(lr >> 2) * 9248 + moB * 8 + ((lr * 2) & 7)] = u2;
      s0 += w0; q0 += w0 * w0; s1 += w1; q1 += w1 * w1;
    }
  }
  if (wv < 9) {
    int t = wv + 64;
    int m = t * 16 + lr;
    int ms = m < 1155 ? m : 1155;
    const unsigned short* ab = inAg + ((ms / 34) * 36 + (ms % 34)) * 8;
    f32x4 c0 = {0.f,0.f,0.f,0.f}, c1v = {0.f,0.f,0.f,0.f};
#pragma unroll
    for (int tap = 0; tap < 9; tap++) {
      f16x8 av = *(const f16x8*)(ab + OFF1[tap]);
      c0  = __builtin_amdgcn_mfma_f32_16x16x32_f16(av, w1f[0][tap], c0, 0, 0, 0);
      c1v = __builtin_amdgcn_mfma_f32_16x16x32_f16(av, w1f[1][tap], c1v, 0, 0, 0);
    }
#pragma unroll
    for (int r = 0; r < 4; r++) {
      int mo = t * 16 + lq * 4 + r;
      if (mo < 1156) {
        float v0 = c0[r], v1 = c1v[r];
        unsigned u = (unsigned)__half_as_ushort(__float2half(v0))
                   | ((unsigned)__half_as_ushort(__float2half(v1)) << 16);
        *(unsigned*)&yB[(lr >> 2) * 9248 + mo * 8 + ((lr * 2) & 7)] = u;
        s0 += v0; q0 += v0 * v0; s1 += v1; q1 += v1 * v1;
      }
    }
  }
#pragma unroll
  for (int off = 16; off < 64; off <<= 1) {
    s0 += __shfl_xor(s0, off); q0 += __shfl_xor(q0, off);
    s1 += __shfl_xor(s1, off); q1 += __shfl_xor(q1, off);
  }
  if (ln < 16) {
    atomicAdd(&statA[ln], s0);      atomicAdd(&statA[16 + ln], q0);
    atomicAdd(&statA[32 + ln], s1); atomicAdd(&statA[48 + ln], q1);
  }
  __syncthreads();
  if (tid < 32) {
    int cti = tid >> 4, lri = tid & 15;   // ch = 2*lri + cti
    float s = statA[cti * 32 + lri];
    float q = statA[cti * 32 + 16 + lri];
    int ch = 2 * lri + cti;
    float mu = s * (1.f / 1156.f);
    float var = q * (1.f / 1156.f) - mu * mu;
    float a_ = rsqrtf(var + 1e-5f) * g1[ch];
    aL[ch] = a_; cL[ch] = b1[ch] - mu * a_;
  }
  if (tid < 16) statA[tid] = 0.f;
  __syncthreads();

  {
    int g = tid >> 8, ocb = g * 8;
    unsigned short* yg = yB + g * 9248;
    for (int pix = (tid & 255); pix < 1156; pix += 256) {
      f16x8 raw = *(const f16x8*)&yg[pix * 8];
      f16x8 outv;
#pragma unroll
      for (int e = 0; e < 8; e++) {
        float v = (float)raw[e];
        outv[e] = (_Float16)fmaxf(v * aL[ocb + e] + cL[ocb + e], 0.f);
      }
      *(f16x8*)&yg[pix * 8] = outv;
    }
  }
  __syncthreads();

  f16x8 w2f[9];
#pragma unroll
  for (int tap = 0; tap < 9; tap++)
    w2f[tap] = *(const f16x8*)&w2frag[(tap * 64 + ln) * 8];

  constexpr int OFF2[9] = {0, 8, 16, 272, 280, 288, 544, 552, 560};
  const unsigned short* yBg = yB + lq * 9248;
  float s2 = 0.f, q2 = 0.f;
#pragma unroll
  for (int t0 = 0; t0 < 2; t0++) {
    const int tA = wv + t0 * 32, tB = tA + 16;
    const int mA = tA * 16 + lr, mB = tB * 16 + lr;
    const unsigned short* abA = yBg + ((mA >> 5) * 34 + (mA & 31)) * 8;
    const unsigned short* abB = yBg + ((mB >> 5) * 34 + (mB & 31)) * 8;
    f32x4 ccA = {0.f,0.f,0.f,0.f}, ccB = {0.f,0.f,0.f,0.f};
#pragma unroll
    for (int tap = 0; tap < 9; tap++) {
      f16x8 avA = *(const f16x8*)(abA + OFF2[tap]);
      f16x8 avB = *(const f16x8*)(abB + OFF2[tap]);
      ccA = __builtin_amdgcn_mfma_f32_16x16x32_f16(avA, w2f[tap], ccA, 0, 0, 0);
      ccB = __builtin_amdgcn_mfma_f32_16x16x32_f16(avB, w2f[tap], ccB, 0, 0, 0);
    }
#pragma unroll
    for (int r = 0; r < 4; r++) {
      float vA = ccA[r], vB = ccB[r];
      s2 += vA + vB; q2 += vA * vA + vB * vB;
      if (lr < 8) {
        transF[lr * 1032 + tA * 16 + lq * 4 + r] = vA;
        transF[lr * 1032 + tB * 16 + lq * 4 + r] = vB;
      }
    }
  }
#pragma unroll
  for (int off = 16; off < 64; off <<= 1) {
    s2 += __shfl_xor(s2, off); q2 += __shfl_xor(q2, off);
  }
  if (ln < 8) { atomicAdd(&statA[ln], s2); atomicAdd(&statA[8 + ln], q2); }
  __syncthreads();
  if (tid < 8) {
    float s = statA[tid], q = statA[8 + tid];
    float mu = s * (1.f / 1024.f);
    float var = q * (1.f / 1024.f) - mu * mu;
    float a_ = rsqrtf(var + 1e-5f) * g2[tid];
    aL[tid] = a_; cL[tid] = b2[tid] - mu * a_;
  }
  __syncthreads();

  {
    int oc = tid >> 7, p8 = (tid & 127) << 3;
    float a_ = aL[oc], c_ = cL[oc];
    f16x8 o;
#pragma unroll
    for (int e = 0; e < 8; e++) {
      float v = transF[oc * 1032 + p8 + e];
      o[e] = (_Float16)(1.f / (1.f + __expf(-(v * a_ + c_))));
    }
    *(f16x8*)&wout[((size_t)oc << 20) + ((size_t)p << 10) + p8] = o;
  }
}

// ---------------- fused attention (r16 verbatim) -------------------------------
__global__ __launch_bounds__(256) void attn_kernel(
    const unsigned short* __restrict__ qkv,  // bf16 bits [8192][1536]
    const __half* __restrict__ wppe,         // f16 [8][1024][1024]
    __half* __restrict__ oh)                 // f16 [8192][512] = (b,n,h,d)
{
  __shared__ __align__(16) unsigned short k_lds[64 * 72];
  __shared__ __align__(16) unsigned short v_lds[64 * 72]; // transposed [d][m ^ swz]
  __shared__ __align__(16) unsigned short p_lds[4 * 16 * 72];
  const int tid = threadIdx.x;
  const int wv = tid >> 6, ln = tid & 63;
  const int lr = ln & 15, lq = ln >> 4;
  const int b = blockIdx.y >> 3, h = blockIdx.y & 7;
  const int n0 = blockIdx.x << 6;

  const size_t qoff = (size_t)((b << 10) + n0 + (wv << 4) + lr) * 1536 + (h << 6);
  bf16x8 qf0 = *(const bf16x8*)(qkv + qoff + lq * 8);
  bf16x8 qf1 = *(const bf16x8*)(qkv + qoff + 32 + lq * 8);

  f32x4 acc[4];
#pragma unroll
  for (int dt = 0; dt < 4; dt++) acc[dt] = (f32x4){0.f, 0.f, 0.f, 0.f};
  float den[4] = {0.f, 0.f, 0.f, 0.f};
  const __half* wp = wppe + ((size_t)h << 20);

  for (int m0 = 0; m0 < 1024; m0 += 64) {
    __syncthreads();
    float wpre[4][4];
#pragma unroll
    for (int mt = 0; mt < 4; mt++)
#pragma unroll
      for (int reg = 0; reg < 4; reg++)
        wpre[mt][reg] = __half2float(
            wp[(size_t)(n0 + (wv << 4) + lq * 4 + reg) * 1024 + (m0 + mt * 16 + lr)]);
    for (int t = tid; t < 512; t += 256) {
      int m = t >> 3, dq = t & 7;
      const unsigned short* kr = qkv + (size_t)((b << 10) + m0 + m) * 1536 + 512 + (h << 6) + dq * 8;
      *(uint4*)&k_lds[m * 72 + dq * 8] = *(const uint4*)kr;
      uint4 vvv = *(const uint4*)(kr + 512);
      unsigned short tmp[8];
      *(uint4*)tmp = vvv;
#pragma unroll
      for (int i = 0; i < 8; i++) {
        int d = dq * 8 + i;
        v_lds[d * 72 + (m ^ (((d >> 3) & 7) << 3))] = tmp[i];
      }
    }
    __syncthreads();

    f32x4 s[4];
#pragma unroll
    for (int mt = 0; mt < 4; mt++) {
      const unsigned short* kb = &k_lds[(mt * 16 + lr) * 72 + lq * 8];
      f32x4 cz = (f32x4){0.f, 0.f, 0.f, 0.f};
      cz = __builtin_amdgcn_mfma_f32_16x16x32_bf16(qf0, *(const bf16x8*)kb, cz, 0, 0, 0);
      cz = __builtin_amdgcn_mfma_f32_16x16x32_bf16(qf1, *(const bf16x8*)(kb + 32), cz, 0, 0, 0);
      s[mt] = cz;
    }
#pragma unroll
    for (int mt = 0; mt < 4; mt++)
#pragma unroll
      for (int reg = 0; reg < 4; reg++) {
        int rrow = lq * 4 + reg;
        float pv = wpre[mt][reg] * __expf(s[mt][reg] * 0.125f);
        den[reg] += pv;
        p_lds[((wv << 4) + rrow) * 72 + mt * 16 + lr] = f2bf(pv);
      }
    const unsigned short* pb = &p_lds[((wv << 4) + lr) * 72];
    bf16x8 pa0 = *(const bf16x8*)(pb + lq * 8);
    bf16x8 pa1 = *(const bf16x8*)(pb + 32 + lq * 8);
#pragma unroll
    for (int dt = 0; dt < 4; dt++) {
      int d = dt * 16 + lr;
      int sw = ((d >> 3) & 7) << 3;
      const unsigned short* vb = &v_lds[d * 72];
      acc[dt] = __builtin_amdgcn_mfma_f32_16x16x32_bf16(pa0, *(const bf16x8*)(vb + ((lq * 8) ^ sw)), acc[dt], 0, 0, 0);
      acc[dt] = __builtin_amdgcn_mfma_f32_16x16x32_bf16(pa1, *(const bf16x8*)(vb + ((32 + lq * 8) ^ sw)), acc[dt], 0, 0, 0);
    }
  }
#pragma unroll
  for (int off = 1; off < 16; off <<= 1)
#pragma unroll
    for (int reg = 0; reg < 4; reg++) den[reg] += __shfl_xor(den[reg], off);
#pragma unroll
  for (int dt = 0; dt < 4; dt++)
#pragma unroll
    for (int reg = 0; reg < 4; reg++) {
      size_t row = (size_t)((b << 10) + n0 + (wv << 4) + lq * 4 + reg);
      oh[row * 512 + (h << 6) + dt * 16 + lr] = __float2half(acc[dt][reg] / den[reg]);
    }
}

// ---------------------------------------------------------------------------
extern "C" void kernel_launch(void* const* d_in, const int* in_sizes, int n_in,
                              void* d_out, int out_size, void* d_ws, size_t ws_size,
                              hipStream_t stream) {
  (void)in_sizes; (void)n_in; (void)out_size; (void)ws_size;
  const float* x     = (const float*)d_in[0];
  const float* rpe   = (const float*)d_in[1];
  const float* wqkv  = (const float*)d_in[2];
  const float* wproj = (const float*)d_in[3];
  const float* bproj = (const float*)d_in[4];
  const float* c1w   = (const float*)d_in[5];
  // d_in[6] = c1b: cancels exactly in the following instance-norm
  const float* g1w   = (const float*)d_in[7];
  const float* g1b   = (const float*)d_in[8];
  const float* c2w   = (const float*)d_in[9];
  // d_in[10] = c2b: cancels likewise
  const float* g2w   = (const float*)d_in[11];
  const float* g2b   = (const float*)d_in[12];
  float* out = (float*)d_out;

  char* ws = (char*)d_ws;
  unsigned short* qkv_bf = (unsigned short*)ws;              // 25,165,824 B
  __half* wppe_h = (__half*)(ws + 25165824);                 // 16,777,216 B
  __half* oh_h   = (__half*)(ws + 41943040);                 // 8,388,608 B
  unsigned short* w1frag = (unsigned short*)(ws + 50331648); // 18,432 B
  unsigned short* w2frag = (unsigned short*)(ws + 50350080); // 9,216 B
  __half* wqkvh  = (__half*)(ws + 50359296);                 // 1,572,864 B
  __half* wprojh = (__half*)(ws + 51932160);                 // 524,288 B
  __half* xh     = (__half*)(ws + 52456448);                 // 8,388,608 B

  // 0) prep: conv fragments + f16 conversion of x/wqkv/wproj
  prep_all<<<5184, 256, 0, stream>>>(c1w, c2w, x, wqkv, wproj,
                                     w1frag, w2frag, xh, wqkvh, wprojh);

  // 1) qkv = x @ wqkv^T -> bf16 (A f16, B f16)
  gemm_f16_bt<true><<<dim3(12, 64), 256, 0, stream>>>(
      xh, wqkvh, qkv_bf, nullptr, 8192, 1536, 512);

  // 2) fused conv1+IN+relu+conv2+IN+sigmoid -> w (f16)
  const int ldsC = 157440;
  hipFuncSetAttribute(reinterpret_cast<const void*>(&conv_fused3),
                      hipFuncAttributeMaxDynamicSharedMemorySize, ldsC);
  conv_fused3<<<1024, 1024, ldsC, stream>>>(rpe, w1frag, w2frag, g1w, g1b, g2w, g2b, wppe_h);

  // 3) fused attention -> oh f16
  attn_kernel<<<dim3(16, 64), 256, 0, stream>>>(qkv_bf, wppe_h, oh_h);

  // 4) out = oh @ wproj^T + bproj (A f16, B f16)
  gemm_f16_bt<false><<<dim3(4, 64), 256, 0, stream>>>(
      oh_h, wprojh, out, bproj, 8192, 512, 512);
}